// Round 6
// baseline (102.622 us; speedup 1.0000x reference)
//
#include <hip/hip_runtime.h>

// EmbeddingShard: out[n, :] = (W_full[x[n], :] + sum_s b[s, :]) / SHARDS
//   x: int32 [16384], W: fp32 [50400, 4096], b: fp32 [8, 4096]
//   out: fp32 [16384, 4096]
// Mapping: wave-owns-2-CONSECUTIVE-tokens. 8192 waves; each wave streams two
// adjacent 16 KB output rows (one contiguous 32 KB NT-write span) while
// gathering two random W rows. Bias presummed into d_ws (16 KB, L1-resident).

#define IN_DIM   50400
#define OUT_DIM  4096
#define SHARDS   8
#define N_TOK    16384

#define BLOCKS   2048            // 8 blocks/CU (32 waves/CU = max occupancy)
#define THREADS  256
#define SLOT4    (OUT_DIM / 4)   // 1024 float4 per row

typedef float f4 __attribute__((ext_vector_type(4)));

// Kernel 1: bsum[j] = (1/SHARDS) * sum_s b[s][j]  (4096 floats into d_ws)
__global__ __launch_bounds__(256) void bias_sum_kernel(const float* __restrict__ b,
                                                       float* __restrict__ bsum) {
    int j = blockIdx.x * blockDim.x + threadIdx.x;
    if (j < OUT_DIM) {
        float s = 0.0f;
#pragma unroll
        for (int sd = 0; sd < SHARDS; ++sd) s += b[sd * OUT_DIM + j];
        bsum[j] = s * (1.0f / SHARDS);
    }
}

// Kernel 2: wave wv owns tokens {2wv, 2wv+1}; contiguous 32 KB write region.
__global__ __launch_bounds__(256) void gather_rows_kernel(const int* __restrict__ x,
                                                          const f4* __restrict__ W4,
                                                          const f4* __restrict__ bsum4,
                                                          f4* __restrict__ out4) {
    const int lane = threadIdx.x & 63;
    const int wv   = __builtin_amdgcn_readfirstlane((blockIdx.x * THREADS + threadIdx.x) >> 6);
    const int n0 = 2 * wv;                // adjacent tokens
    const int n1 = 2 * wv + 1;
    const int r0 = x[n0];                 // uniform -> s_load
    const int r1 = x[n1];

    const f4* __restrict__ w0 = W4 + (size_t)r0 * SLOT4;
    const f4* __restrict__ w1 = W4 + (size_t)r1 * SLOT4;
    f4* __restrict__ o0 = out4 + (size_t)n0 * SLOT4;
    f4* __restrict__ o1 = out4 + (size_t)n1 * SLOT4;

#pragma unroll 4
    for (int it = 0; it < 16; ++it) {
        const int j = lane + it * 64;     // sequential 1 KB chunks per wave
        const f4 a  = w0[j];
        const f4 c  = w1[j];
        const f4 bb = bsum4[j];           // L1-resident (16 KB)
        __builtin_nontemporal_store(a * 0.125f + bb, &o0[j]);
        __builtin_nontemporal_store(c * 0.125f + bb, &o1[j]);
    }
}

extern "C" void kernel_launch(void* const* d_in, const int* in_sizes, int n_in,
                              void* d_out, int out_size, void* d_ws, size_t ws_size,
                              hipStream_t stream) {
    const int*   x = (const int*)d_in[0];    // [16384]
    const float* W = (const float*)d_in[1];  // [50400*4096]
    const float* b = (const float*)d_in[2];  // [8*4096]
    float* out  = (float*)d_out;             // [16384*4096]
    float* bsum = (float*)d_ws;              // 4096 floats scratch

    bias_sum_kernel<<<OUT_DIM / 256, 256, 0, stream>>>(b, bsum);
    gather_rows_kernel<<<BLOCKS, THREADS, 0, stream>>>(
        x, (const f4*)W, (const f4*)bsum, (f4*)out);
}

// Round 7
// 99.893 us; speedup vs baseline: 1.0273x; 1.0273x over previous
//
#include <hip/hip_runtime.h>

// EmbeddingShard: out[n, :] = (W_full[x[n], :] + sum_s b[s, :]) / SHARDS
//   x: int32 [16384], W: fp32 [50400, 4096], b: fp32 [8, 4096]
//   out: fp32 [16384, 4096]
// Mapping: wave-owns-row (R5 best). NEW: phase-separated 8 KB read bursts /
// 8 KB NT-write bursts per row to cut DRAM read<->write turnarounds.
// Bias presummed into d_ws (16 KB, L1-resident).

#define IN_DIM   50400
#define OUT_DIM  4096
#define SHARDS   8
#define N_TOK    16384

#define BLOCKS   2048            // 8 blocks/CU (32 waves/CU target)
#define THREADS  256
#define NWAVES   (BLOCKS * THREADS / 64)   // 8192 -> 2 tokens per wave
#define SLOT4    (OUT_DIM / 4)             // 1024 float4 per row

typedef float f4 __attribute__((ext_vector_type(4)));

// Kernel 1: bsum[j] = (1/SHARDS) * sum_s b[s][j]  (4096 floats into d_ws)
__global__ __launch_bounds__(256) void bias_sum_kernel(const float* __restrict__ b,
                                                       float* __restrict__ bsum) {
    int j = blockIdx.x * blockDim.x + threadIdx.x;
    if (j < OUT_DIM) {
        float s = 0.0f;
#pragma unroll
        for (int sd = 0; sd < SHARDS; ++sd) s += b[sd * OUT_DIM + j];
        bsum[j] = s * (1.0f / SHARDS);
    }
}

// Kernel 2: wave wv owns tokens {wv, wv+8192}. Per row: two phases of
// {8x1KB register-burst read, then 8x1KB NT-store burst}.
__global__ __launch_bounds__(256) void gather_rows_kernel(const int* __restrict__ x,
                                                          const f4* __restrict__ W4,
                                                          const f4* __restrict__ bsum4,
                                                          f4* __restrict__ out4) {
    const int lane = threadIdx.x & 63;
    const int wv   = __builtin_amdgcn_readfirstlane((blockIdx.x * THREADS + threadIdx.x) >> 6);

#pragma unroll
    for (int t = 0; t < 2; ++t) {
        const int n = wv + t * NWAVES;          // token index
        const int r = x[n];                      // uniform -> s_load
        const f4* __restrict__ wr = W4 + (size_t)r * SLOT4;
        f4* __restrict__ or_ = out4 + (size_t)n * SLOT4;

#pragma unroll
        for (int c = 0; c < 2; ++c) {            // two 8 KB half-rows
            const int base = lane + c * 512;     // f4 index of this chunk start
            f4 v0, v1, v2, v3, v4, v5, v6, v7;   // 8 KB burst read (8 loads in flight)
            v0 = wr[base + 0 * 64];
            v1 = wr[base + 1 * 64];
            v2 = wr[base + 2 * 64];
            v3 = wr[base + 3 * 64];
            v4 = wr[base + 4 * 64];
            v5 = wr[base + 5 * 64];
            v6 = wr[base + 6 * 64];
            v7 = wr[base + 7 * 64];
            // 8 KB NT-write burst (bias from L1)
            __builtin_nontemporal_store(v0 * 0.125f + bsum4[base + 0 * 64], &or_[base + 0 * 64]);
            __builtin_nontemporal_store(v1 * 0.125f + bsum4[base + 1 * 64], &or_[base + 1 * 64]);
            __builtin_nontemporal_store(v2 * 0.125f + bsum4[base + 2 * 64], &or_[base + 2 * 64]);
            __builtin_nontemporal_store(v3 * 0.125f + bsum4[base + 3 * 64], &or_[base + 3 * 64]);
            __builtin_nontemporal_store(v4 * 0.125f + bsum4[base + 4 * 64], &or_[base + 4 * 64]);
            __builtin_nontemporal_store(v5 * 0.125f + bsum4[base + 5 * 64], &or_[base + 5 * 64]);
            __builtin_nontemporal_store(v6 * 0.125f + bsum4[base + 6 * 64], &or_[base + 6 * 64]);
            __builtin_nontemporal_store(v7 * 0.125f + bsum4[base + 7 * 64], &or_[base + 7 * 64]);
        }
    }
}

extern "C" void kernel_launch(void* const* d_in, const int* in_sizes, int n_in,
                              void* d_out, int out_size, void* d_ws, size_t ws_size,
                              hipStream_t stream) {
    const int*   x = (const int*)d_in[0];    // [16384]
    const float* W = (const float*)d_in[1];  // [50400*4096]
    const float* b = (const float*)d_in[2];  // [8*4096]
    float* out  = (float*)d_out;             // [16384*4096]
    float* bsum = (float*)d_ws;              // 4096 floats scratch

    bias_sum_kernel<<<OUT_DIM / 256, 256, 0, stream>>>(b, bsum);
    gather_rows_kernel<<<BLOCKS, THREADS, 0, stream>>>(
        x, (const f4*)W, (const f4*)bsum, (f4*)out);
}

// Round 8
// 96.779 us; speedup vs baseline: 1.0604x; 1.0322x over previous
//
#include <hip/hip_runtime.h>

// EmbeddingShard: out[n, :] = (W_full[x[n], :] + sum_s b[s, :]) / SHARDS
//   x: int32 [16384], W: fp32 [50400, 4096], b: fp32 [8, 4096]
//   out: fp32 [16384, 4096]
// BEST CONFIG (R5): wave-owns-row. 8192 waves; each wave streams 2 full 16 KB
// rows (tokens wv and wv+8192), 1 KB per iteration, 2 interleaved streams for
// MLP. Bias presummed into d_ws (16 KB, L1-resident). NT stores for output.
// Probed and rejected: consecutive-token writes (R6 -6%), 8KB burst phase
// separation (R7 -4%), idx scalarization depth (R4 neutral).

#define IN_DIM   50400
#define OUT_DIM  4096
#define SHARDS   8
#define N_TOK    16384

#define BLOCKS   2048            // 8 blocks/CU (32 waves/CU = max occupancy)
#define THREADS  256
#define NWAVES   (BLOCKS * THREADS / 64)   // 8192 -> 2 tokens per wave
#define SLOT4    (OUT_DIM / 4)             // 1024 float4 per row

typedef float f4 __attribute__((ext_vector_type(4)));

// Kernel 1: bsum[j] = (1/SHARDS) * sum_s b[s][j]  (4096 floats into d_ws)
__global__ __launch_bounds__(256) void bias_sum_kernel(const float* __restrict__ b,
                                                       float* __restrict__ bsum) {
    int j = blockIdx.x * blockDim.x + threadIdx.x;
    if (j < OUT_DIM) {
        float s = 0.0f;
#pragma unroll
        for (int sd = 0; sd < SHARDS; ++sd) s += b[sd * OUT_DIM + j];
        bsum[j] = s * (1.0f / SHARDS);
    }
}

// Kernel 2: each wave owns tokens {wv, wv+8192}; walks both 16 KB rows
// sequentially, 1 KB (64 lanes x 16 B) per iteration, interleaved for MLP.
__global__ __launch_bounds__(256) void gather_rows_kernel(const int* __restrict__ x,
                                                          const f4* __restrict__ W4,
                                                          const f4* __restrict__ bsum4,
                                                          f4* __restrict__ out4) {
    const int lane = threadIdx.x & 63;
    const int wv   = __builtin_amdgcn_readfirstlane((blockIdx.x * THREADS + threadIdx.x) >> 6);
    const int n0 = wv;                    // token 0
    const int n1 = wv + NWAVES;           // token 1
    const int r0 = x[n0];                 // uniform -> s_load
    const int r1 = x[n1];

    const f4* __restrict__ w0 = W4 + (size_t)r0 * SLOT4;
    const f4* __restrict__ w1 = W4 + (size_t)r1 * SLOT4;
    f4* __restrict__ o0 = out4 + (size_t)n0 * SLOT4;
    f4* __restrict__ o1 = out4 + (size_t)n1 * SLOT4;

#pragma unroll 4
    for (int it = 0; it < 16; ++it) {
        const int j = lane + it * 64;     // sequential 1 KB chunks per wave
        const f4 a  = w0[j];
        const f4 c  = w1[j];
        const f4 bb = bsum4[j];           // L1-resident (16 KB)
        __builtin_nontemporal_store(a * 0.125f + bb, &o0[j]);
        __builtin_nontemporal_store(c * 0.125f + bb, &o1[j]);
    }
}

extern "C" void kernel_launch(void* const* d_in, const int* in_sizes, int n_in,
                              void* d_out, int out_size, void* d_ws, size_t ws_size,
                              hipStream_t stream) {
    const int*   x = (const int*)d_in[0];    // [16384]
    const float* W = (const float*)d_in[1];  // [50400*4096]
    const float* b = (const float*)d_in[2];  // [8*4096]
    float* out  = (float*)d_out;             // [16384*4096]
    float* bsum = (float*)d_ws;              // 4096 floats scratch

    bias_sum_kernel<<<OUT_DIM / 256, 256, 0, stream>>>(b, bsum);
    gather_rows_kernel<<<BLOCKS, THREADS, 0, stream>>>(
        x, (const f4*)W, (const f4*)bsum, (f4*)out);
}